// Round 6
// baseline (253.162 us; speedup 1.0000x reference)
//
#include <hip/hip_runtime.h>
#include <math.h>

namespace {

constexpr int B = 16, CIN = 8, D = 16, H = 128, W = 128;
constexpr float INV_CNT = 1.0f / 27783.0f;   // 1/(7*63*63)
constexpr int HW = H * W, DHW = D * HW;

typedef short v8s  __attribute__((ext_vector_type(8)));   // 8 bf16
typedef float v16f __attribute__((ext_vector_type(16)));  // 32x32 acc

// LDS map (all linear, no swizzle):
//  X tile [d16][h4][w128][ci8] bf16 : 0      .. 131072
//  WB [pair14][lane64][ci8] bf16    : 131072 .. 145408
//  PM pm-exchange, 2 parity bufs    : 145408 .. 161792 (2 x 4q x 64l x 32B)
//  RED 4 floats                     : 161792 .. 161856  (<= 163840 LDS/CU)
constexpr int WB_OFF  = 131072;
constexpr int PM_OFF  = WB_OFF + 14336;
constexpr int RED_OFF = PM_OFF + 16384;
constexpr int LDS_BYTES = RED_OFF + 64;

__device__ inline unsigned short f2bf(float f) {          // RTN-even fp32->bf16
    unsigned int x = __builtin_bit_cast(unsigned int, f);
    return (unsigned short)((x + 0x7FFFu + ((x >> 16) & 1u)) >> 16);
}

__device__ inline void stage_planes(char* smem, const float* xb, int ph,
                                    int dlo, int nplanes, int t) {
    for (int s = t; s < nplanes * 512; s += 512) {
        const int d = dlo + (s >> 9), h = (s >> 7) & 3, w = s & 127;
        const float* xp = xb + d * HW + (2 * ph + h) * W + w;
        unsigned int v[4];
        #pragma unroll
        for (int j = 0; j < 4; ++j) {
            unsigned short b0 = f2bf(xp[(2 * j) * DHW]);
            unsigned short b1 = f2bf(xp[(2 * j + 1) * DHW]);
            v[j] = (unsigned int)b0 | ((unsigned int)b1 << 16);
        }
        *reinterpret_cast<uint4*>(smem + ((d * 4 + h) * 128 + w) * 16) =
            uint4{v[0], v[1], v[2], v[3]};
    }
}

// One block per (b, ph). 8 waves: wv = (q<<1)|dd, q = w-quarter (32 w), dd = pool-d.
// MFMA rows = 32 CONTIGUOUS w at fixed (hh,dd) -> A-reads are contiguous 512B runs.
// acc0: hh=0, acc1: hh=1. Window max needs both dd -> pm exchange via LDS per pd.
__global__ __launch_bounds__(512, 2) void conv_mfma_kernel(
    const float* __restrict__ x,
    const float* __restrict__ wgt,      // [32][8][3][3][3]
    const float* __restrict__ cbias,    // [32]
    float* __restrict__ partials)       // [1008]
{
    __shared__ __align__(16) char smem[LDS_BYTES];

    const int bid = blockIdx.x;                    // 1008 = 8 * 126 exact
    const int logical = (bid & 7) * 126 + (bid >> 3);
    const int ph = logical % 63;
    const int b  = logical / 63;

    const int t = threadIdx.x, lane = t & 63, wv = t >> 6;
    const int dd = wv & 1, q = wv >> 1, w0 = 32 * q;
    const int r = lane & 31, half = lane >> 5;

    // ---- stage WB: lane l of pair p = W[cout=l&31][ci 0..7][tap=2p+(l>>5)] ----
    for (int pr = t; pr < 14 * 64; pr += 512) {
        const int p = pr >> 6, l = pr & 63;
        const int tap = 2 * p + (l >> 5), cout = l & 31;
        uint4 pk = {0u, 0u, 0u, 0u};
        if (tap < 27) {
            unsigned int v[4];
            #pragma unroll
            for (int j = 0; j < 4; ++j) {
                unsigned short b0 = f2bf(wgt[(cout * CIN + 2 * j) * 27 + tap]);
                unsigned short b1 = f2bf(wgt[(cout * CIN + 2 * j + 1) * 27 + tap]);
                v[j] = (unsigned int)b0 | ((unsigned int)b1 << 16);
            }
            pk = uint4{v[0], v[1], v[2], v[3]};
        }
        *reinterpret_cast<uint4*>(smem + WB_OFF + pr * 16) = pk;
    }

    const float* xb = x + (size_t)b * CIN * DHW;
    stage_planes(smem, xb, ph, 0, 6, t);           // pd0 needs d0..3, pd1 d2..5
    __syncthreads();

    // ---- B fragments to registers ----
    v8s Bf[14];
    #pragma unroll
    for (int ks = 0; ks < 14; ++ks)
        Bf[ks] = *reinterpret_cast<const v8s*>(smem + WB_OFF + (ks * 64 + lane) * 16);

    // ---- per-lane A byte offsets (kd,kh,kw of this half's tap; w = w0+r+kw) ----
    int offA[14];
    #pragma unroll
    for (int ks = 0; ks < 14; ++ks) {
        int tap = 2 * ks + half; if (tap > 26) tap = 26;  // pad: Bf==0 anyway
        const int kd = tap / 9, kh = (tap % 9) / 3, kw = tap % 3;
        offA[ks] = kd * 8192 + kh * 2048 + (w0 + r + kw) * 16;
    }

    const float cb = cbias[lane & 31];
    float lsum = 0.f;

    #pragma unroll 1
    for (int pd = 0; pd < 7; ++pd) {
        v16f acc0, acc1;
        #pragma unroll
        for (int i = 0; i < 16; ++i) { acc0[i] = 0.f; acc1[i] = 0.f; }
        const int cbase = (2 * pd + dd) * 8192;

        #pragma unroll
        for (int ks = 0; ks < 14; ++ks) {
            const v8s A0 = *reinterpret_cast<const v8s*>(smem + cbase + offA[ks]);
            const v8s A1 = *reinterpret_cast<const v8s*>(smem + cbase + offA[ks] + 2048);
            acc0 = __builtin_amdgcn_mfma_f32_32x32x16_bf16(A0, Bf[ks], acc0, 0, 0, 0);
            acc1 = __builtin_amdgcn_mfma_f32_32x32x16_bf16(A1, Bf[ks], acc1, 0, 0, 0);
        }

        // per-lane window maxes over (hh, ww): reg pairs (2i,2i+1) = w rows (2j,2j+1)
        float pm[8];
        #pragma unroll
        for (int i = 0; i < 8; ++i)
            pm[i] = fmaxf(fmaxf(acc0[2 * i], acc0[2 * i + 1]),
                          fmaxf(acc1[2 * i], acc1[2 * i + 1]));

        char* pmbuf = smem + PM_OFF + (pd & 1) * 8192 + (q * 64 + lane) * 32;
        if (dd == 1) {
            *reinterpret_cast<float4*>(pmbuf)      = float4{pm[0], pm[1], pm[2], pm[3]};
            *reinterpret_cast<float4*>(pmbuf + 16) = float4{pm[4], pm[5], pm[6], pm[7]};
        }
        if (pd <= 4) stage_planes(smem, xb, ph, 2 * pd + 6, 2, t);  // for pd+2
        __syncthreads();

        if (dd == 0) {
            const float4 pa = *reinterpret_cast<const float4*>(pmbuf);
            const float4 pb = *reinterpret_cast<const float4*>(pmbuf + 16);
            const float pp[8] = {pa.x, pa.y, pa.z, pa.w, pb.x, pb.y, pb.z, pb.w};
            #pragma unroll
            for (int i = 0; i < 8; ++i) {
                const int pw = 16 * q + (i & 1) + 4 * (i >> 1) + 2 * half;
                const float m = fmaxf(pm[i], pp[i]);
                if (pw < 63) lsum += (m + cb) * 0.5f;
            }
        }
    }

    #pragma unroll
    for (int o = 32; o > 0; o >>= 1) lsum += __shfl_xor(lsum, o, 64);
    if (dd == 0 && lane == 0)
        reinterpret_cast<float*>(smem + RED_OFF)[q] = lsum;
    __syncthreads();
    if (t == 0) {
        float s = 0.f;
        #pragma unroll
        for (int i = 0; i < 4; ++i) s += reinterpret_cast<float*>(smem + RED_OFF)[i];
        partials[logical] = s;
    }
}

// out[b] = INV_CNT * sum_ph partials[b*63+ph] + sum_c bias[c]
__global__ void finalize_kernel(const float* __restrict__ partials,
                                const float* __restrict__ bias,
                                float* __restrict__ out)
{
    const int t = threadIdx.x;          // 512 = 16 b-groups x 32 lanes
    const int b = t >> 5, l = t & 31;
    float s = 0.f;
    for (int j = l; j < 63; j += 32) s += partials[b * 63 + j];
    s = s * INV_CNT + bias[l];
    #pragma unroll
    for (int o = 16; o > 0; o >>= 1) s += __shfl_xor(s, o, 32);
    if (l == 0) out[b] = s;
}

} // namespace

extern "C" void kernel_launch(void* const* d_in, const int* in_sizes, int n_in,
                              void* d_out, int out_size, void* d_ws, size_t ws_size,
                              hipStream_t stream) {
    const float* x     = (const float*)d_in[0];
    const float* wgt   = (const float*)d_in[1];
    const float* cbias = (const float*)d_in[2];
    const float* bias  = (const float*)d_in[3];
    float* out      = (float*)d_out;
    float* partials = (float*)d_ws;     // 1008 floats

    hipLaunchKernelGGL(conv_mfma_kernel, dim3(B * 63), dim3(512), 0, stream,
                       x, wgt, cbias, partials);
    hipLaunchKernelGGL(finalize_kernel, dim3(1), dim3(512), 0, stream,
                       partials, bias, out);
}

// Round 7
// 239.669 us; speedup vs baseline: 1.0563x; 1.0563x over previous
//
#include <hip/hip_runtime.h>
#include <math.h>

namespace {

constexpr int B = 16, CIN = 8, D = 16, H = 128, W = 128;
constexpr float INV_CNT = 1.0f / 27783.0f;   // 1/(7*63*63)
constexpr int HW = H * W, DHW = D * HW;

typedef short v8s  __attribute__((ext_vector_type(8)));   // 8 bf16
typedef float v16f __attribute__((ext_vector_type(16)));  // 32x32 acc

// LDS map (linear, no swizzle):
//  X slab [d16][h4][w128][ci8] bf16 : 0      .. 131072
//  WB [pair14][lane64][ci8] bf16    : 131072 .. 145408
//  RED 8 floats                     : 145408 .. 145440
constexpr int WB_OFF  = 131072;
constexpr int RED_OFF = WB_OFF + 14336;
constexpr int LDS_BYTES = RED_OFF + 64;      // 145472 -> 1 block/CU, 2 waves/SIMD

__device__ inline unsigned short f2bf(float f) {          // RTN-even fp32->bf16
    unsigned int x = __builtin_bit_cast(unsigned int, f);
    return (unsigned short)((x + 0x7FFFu + ((x >> 16) & 1u)) >> 16);
}

// One block per (b, ph). 8 waves: wv = (pdh<<2)|q -> SIMD q hosts {pdh0,pdh1}.
// Wave owns 32 contiguous w (w0=32q) and ALL of (hh,dd): 4 accumulators
// a[hh][dd]; pooling max over (ww,hh,dd) is fully in-lane -> NO per-pd
// barriers (r6 lesson: per-pd sync + exposed stage latency cost more than
// the bank conflicts it fixed). Rows = contiguous w -> conflict-free b128.
__global__ __launch_bounds__(512, 2) void conv_mfma_kernel(
    const float* __restrict__ x,
    const float* __restrict__ wgt,      // [32][8][3][3][3]
    const float* __restrict__ cbias,    // [32]
    float* __restrict__ partials)       // [1008]
{
    __shared__ __align__(16) char smem[LDS_BYTES];

    const int bid = blockIdx.x;                    // 1008 = 8 * 126 exact
    const int logical = (bid & 7) * 126 + (bid >> 3);
    const int ph = logical % 63;
    const int b  = logical / 63;

    const int t = threadIdx.x, lane = t & 63, wv = t >> 6;
    const int q = wv & 3, pdh = wv >> 2, w0 = 32 * q;
    const int r = lane & 31, half = lane >> 5;

    // ---- stage WB: lane l of pair p = W[cout=l&31][ci 0..7][tap=2p+(l>>5)] ----
    for (int pr = t; pr < 14 * 64; pr += 512) {
        const int p = pr >> 6, l = pr & 63;
        const int tap = 2 * p + (l >> 5), cout = l & 31;
        uint4 pk = {0u, 0u, 0u, 0u};
        if (tap < 27) {
            unsigned int v[4];
            #pragma unroll
            for (int j = 0; j < 4; ++j) {
                unsigned short b0 = f2bf(wgt[(cout * CIN + 2 * j) * 27 + tap]);
                unsigned short b1 = f2bf(wgt[(cout * CIN + 2 * j + 1) * 27 + tap]);
                v[j] = (unsigned int)b0 | ((unsigned int)b1 << 16);
            }
            pk = uint4{v[0], v[1], v[2], v[3]};
        }
        *reinterpret_cast<uint4*>(smem + WB_OFF + pr * 16) = pk;
    }

    // ---- stage full x slab upfront: 8192 sites, 8 ci each, ci innermost ----
    const float* xb = x + (size_t)b * CIN * DHW;
    #pragma unroll 4
    for (int s = t; s < 8192; s += 512) {
        const int d = s >> 9, h = (s >> 7) & 3, w = s & 127;
        const float* xp = xb + d * HW + (2 * ph + h) * W + w;
        unsigned int v[4];
        #pragma unroll
        for (int j = 0; j < 4; ++j) {
            unsigned short b0 = f2bf(xp[(2 * j) * DHW]);
            unsigned short b1 = f2bf(xp[(2 * j + 1) * DHW]);
            v[j] = (unsigned int)b0 | ((unsigned int)b1 << 16);
        }
        *reinterpret_cast<uint4*>(smem + s * 16) = uint4{v[0], v[1], v[2], v[3]};
    }

    __syncthreads();      // the ONLY barrier before the reduction

    // ---- B fragments to registers ----
    v8s Bf[14];
    #pragma unroll
    for (int ks = 0; ks < 14; ++ks)
        Bf[ks] = *reinterpret_cast<const v8s*>(smem + WB_OFF + (ks * 64 + lane) * 16);

    // ---- per-lane A byte offsets at (dd=0, hh=0); w clamped (pw63 masked) ----
    int offA[14];
    #pragma unroll
    for (int ks = 0; ks < 14; ++ks) {
        int tap = 2 * ks + half; if (tap > 26) tap = 26;   // pad tap: Bf==0
        const int kd = tap / 9, kh = (tap % 9) / 3, kw = tap % 3;
        int w = w0 + r + kw; if (w > 127) w = 127;
        offA[ks] = kd * 8192 + kh * 2048 + w * 16;
    }

    const float cb = cbias[lane & 31];
    const int pd0 = pdh ? 4 : 0;
    const int npd = pdh ? 3 : 4;
    float lsum = 0.f;

    #pragma unroll 1
    for (int pp = 0; pp < npd; ++pp) {
        const int pbase = (pd0 + pp) * 16384;
        v16f a00, a01, a10, a11;         // a[hh][dd]
        #pragma unroll
        for (int i = 0; i < 16; ++i) { a00[i] = 0.f; a01[i] = 0.f; a10[i] = 0.f; a11[i] = 0.f; }

        #pragma unroll
        for (int ks = 0; ks < 14; ++ks) {
            const char* base = smem + pbase + offA[ks];
            const v8s A00 = *reinterpret_cast<const v8s*>(base);            // hh0 dd0
            const v8s A10 = *reinterpret_cast<const v8s*>(base + 2048);     // hh1 dd0
            const v8s A01 = *reinterpret_cast<const v8s*>(base + 8192);     // hh0 dd1
            const v8s A11 = *reinterpret_cast<const v8s*>(base + 10240);    // hh1 dd1
            a00 = __builtin_amdgcn_mfma_f32_32x32x16_bf16(A00, Bf[ks], a00, 0, 0, 0);
            a10 = __builtin_amdgcn_mfma_f32_32x32x16_bf16(A10, Bf[ks], a10, 0, 0, 0);
            a01 = __builtin_amdgcn_mfma_f32_32x32x16_bf16(A01, Bf[ks], a01, 0, 0, 0);
            a11 = __builtin_amdgcn_mfma_f32_32x32x16_bf16(A11, Bf[ks], a11, 0, 0, 0);
        }

        // C row=(reg&3)+8*(reg>>2)+4*half = w-row; window j: regs {2j,2j+1}
        // across all 4 accs; pwl = (j&1)+4*(j>>1)+2*half, pw = 16q+pwl.
        #pragma unroll
        for (int j = 0; j < 8; ++j) {
            float m = fmaxf(fmaxf(a00[2 * j], a00[2 * j + 1]),
                            fmaxf(a10[2 * j], a10[2 * j + 1]));
            m = fmaxf(m, fmaxf(fmaxf(a01[2 * j], a01[2 * j + 1]),
                               fmaxf(a11[2 * j], a11[2 * j + 1])));
            const int pw = 16 * q + (j & 1) + 4 * (j >> 1) + 2 * half;
            if (pw < 63) lsum += (m + cb) * 0.5f;
        }
    }

    #pragma unroll
    for (int o = 32; o > 0; o >>= 1) lsum += __shfl_xor(lsum, o, 64);
    if (lane == 0) reinterpret_cast<float*>(smem + RED_OFF)[wv] = lsum;
    __syncthreads();
    if (t == 0) {
        float s = 0.f;
        #pragma unroll
        for (int i = 0; i < 8; ++i) s += reinterpret_cast<float*>(smem + RED_OFF)[i];
        partials[logical] = s;
    }
}

// out[b] = INV_CNT * sum_ph partials[b*63+ph] + sum_c bias[c]
__global__ void finalize_kernel(const float* __restrict__ partials,
                                const float* __restrict__ bias,
                                float* __restrict__ out)
{
    const int t = threadIdx.x;          // 512 = 16 b-groups x 32 lanes
    const int b = t >> 5, l = t & 31;
    float s = 0.f;
    for (int j = l; j < 63; j += 32) s += partials[b * 63 + j];
    s = s * INV_CNT + bias[l];
    #pragma unroll
    for (int o = 16; o > 0; o >>= 1) s += __shfl_xor(s, o, 32);
    if (l == 0) out[b] = s;
}

} // namespace

extern "C" void kernel_launch(void* const* d_in, const int* in_sizes, int n_in,
                              void* d_out, int out_size, void* d_ws, size_t ws_size,
                              hipStream_t stream) {
    const float* x     = (const float*)d_in[0];
    const float* wgt   = (const float*)d_in[1];
    const float* cbias = (const float*)d_in[2];
    const float* bias  = (const float*)d_in[3];
    float* out      = (float*)d_out;
    float* partials = (float*)d_ws;     // 1008 floats

    hipLaunchKernelGGL(conv_mfma_kernel, dim3(B * 63), dim3(512), 0, stream,
                       x, wgt, cbias, partials);
    hipLaunchKernelGGL(finalize_kernel, dim3(1), dim3(512), 0, stream,
                       partials, bias, out);
}